// Round 7
// baseline (131.149 us; speedup 1.0000x reference)
//
#include <hip/hip_runtime.h>

#define DIM 16
#define LPS 4     // lanes per stream; lane j covers dims [4j, 4j+4)
#define K_TOK 8   // tokens per stream, fully unrolled

// out[b*DIM + d] = bias[d], vectorized float4 (d_out poisoned to 0xAA pre-launch)
__global__ void init_out_kernel(float4* __restrict__ out4,
                                const float* __restrict__ bias,
                                int n4) {
    int i = blockIdx.x * blockDim.x + threadIdx.x;
    if (i < n4) {
        int d = (i & 3) * 4;   // DIM=16 -> 4 float4 per row
        out4[i] = make_float4(bias[d], bias[d + 1], bias[d + 2], bias[d + 3]);
    }
}

// 4 lanes per stream; each lane gathers a float4 (dwordx4) of the 64B row, so
// one wave-instruction fetches 16 distinct rows = 1KB (vs 256B with the
// dword-per-lane layout) -- 4x fewer VMEM instructions for identical traffic.
// Sorted segment_ids -> register run-length accumulate in a float4;
// atomicAdd x4 only at segment boundaries.
__global__ __launch_bounds__(256) void features_linear_kernel(
    const int*   __restrict__ ids,
    const float* __restrict__ ratings,
    const int*   __restrict__ segs,
    const float* __restrict__ weight,
    float*       __restrict__ out,
    int total) {
    int tid = blockIdx.x * blockDim.x + threadIdx.x;
    int j = tid & (LPS - 1);          // lane within stream
    int d0 = j * 4;                   // first dim this lane owns
    int stream_id = tid >> 2;
    int t0 = stream_id * K_TOK;
    if (t0 >= total) return;

    float4 acc = make_float4(0.f, 0.f, 0.f, 0.f);
    int prev = segs[t0];

    if (t0 + K_TOK <= total) {
        const int4*   idv = (const int4*)(ids + t0);
        const float4* rv  = (const float4*)(ratings + t0);
        const int4*   sv  = (const int4*)(segs + t0);

        int4   id0 = idv[0], id1 = idv[1];
        float4 r0  = rv[0],  r1  = rv[1];
        int4   s0  = sv[0],  s1  = sv[1];

        // 8 independent dwordx4 gathers issued before any use
        #define WROW(idx_) (*(const float4*)(weight + (size_t)(idx_) * DIM + d0))
        float4 w0 = WROW(id0.x);
        float4 w1 = WROW(id0.y);
        float4 w2 = WROW(id0.z);
        float4 w3 = WROW(id0.w);
        float4 w4 = WROW(id1.x);
        float4 w5 = WROW(id1.y);
        float4 w6 = WROW(id1.z);
        float4 w7 = WROW(id1.w);
        #undef WROW

        #define FLUSH()                                                    \
            {                                                              \
                float* o = &out[prev * DIM + d0];                          \
                atomicAdd(o + 0, acc.x);                                   \
                atomicAdd(o + 1, acc.y);                                   \
                atomicAdd(o + 2, acc.z);                                   \
                atomicAdd(o + 3, acc.w);                                   \
                acc = make_float4(0.f, 0.f, 0.f, 0.f);                     \
            }
        #define STEP(sv_, wv_, rv_)                                        \
            if ((sv_) != prev) { FLUSH(); prev = (sv_); }                  \
            acc.x = fmaf((wv_).x, (rv_), acc.x);                           \
            acc.y = fmaf((wv_).y, (rv_), acc.y);                           \
            acc.z = fmaf((wv_).z, (rv_), acc.z);                           \
            acc.w = fmaf((wv_).w, (rv_), acc.w);

        STEP(s0.x, w0, r0.x)  STEP(s0.y, w1, r0.y)
        STEP(s0.z, w2, r0.z)  STEP(s0.w, w3, r0.w)
        STEP(s1.x, w4, r1.x)  STEP(s1.y, w5, r1.y)
        STEP(s1.z, w6, r1.z)  STEP(s1.w, w7, r1.w)

        {
            float* o = &out[prev * DIM + d0];
            atomicAdd(o + 0, acc.x);
            atomicAdd(o + 1, acc.y);
            atomicAdd(o + 2, acc.z);
            atomicAdd(o + 3, acc.w);
        }
        #undef STEP
        #undef FLUSH
    } else {
        // generic tail (not hit for TOTAL=819200)
        for (int t = t0; t < total; ++t) {
            int seg = segs[t];
            if (seg != prev) {
                float* o = &out[prev * DIM + d0];
                atomicAdd(o + 0, acc.x);
                atomicAdd(o + 1, acc.y);
                atomicAdd(o + 2, acc.z);
                atomicAdd(o + 3, acc.w);
                acc = make_float4(0.f, 0.f, 0.f, 0.f);
                prev = seg;
            }
            const float4 w = *(const float4*)(weight + (size_t)ids[t] * DIM + d0);
            float r = ratings[t];
            acc.x = fmaf(w.x, r, acc.x);
            acc.y = fmaf(w.y, r, acc.y);
            acc.z = fmaf(w.z, r, acc.z);
            acc.w = fmaf(w.w, r, acc.w);
        }
        float* o = &out[prev * DIM + d0];
        atomicAdd(o + 0, acc.x);
        atomicAdd(o + 1, acc.y);
        atomicAdd(o + 2, acc.z);
        atomicAdd(o + 3, acc.w);
    }
}

extern "C" void kernel_launch(void* const* d_in, const int* in_sizes, int n_in,
                              void* d_out, int out_size, void* d_ws, size_t ws_size,
                              hipStream_t stream) {
    const int*   ids     = (const int*)d_in[0];
    const float* ratings = (const float*)d_in[1];
    const int*   segs    = (const int*)d_in[2];
    // d_in[3] = batch_size scalar (unused; batch = out_size / DIM)
    const float* weight  = (const float*)d_in[4];
    const float* bias    = (const float*)d_in[5];
    float* out = (float*)d_out;

    int total = in_sizes[0];

    // 1) initialize output with bias (vectorized)
    {
        int n4 = out_size / 4;
        int threads = 256;
        int blocks = (n4 + threads - 1) / threads;
        init_out_kernel<<<blocks, threads, 0, stream>>>((float4*)out, bias, n4);
    }

    // 2) gather + segmented sum
    {
        int n_streams = (total + K_TOK - 1) / K_TOK;
        long long n_threads = (long long)n_streams * LPS;
        int threads = 256;
        int blocks = (int)((n_threads + threads - 1) / threads);
        features_linear_kernel<<<blocks, threads, 0, stream>>>(
            ids, ratings, segs, weight, out, total);
    }
}

// Round 8
// 116.008 us; speedup vs baseline: 1.1305x; 1.1305x over previous
//
#include <hip/hip_runtime.h>

#define DIM 16
#define K_TOK 16   // tokens per 16-lane stream; fully unrolled

// out[b*DIM + d] = bias[d], vectorized float4 (d_out poisoned to 0xAA pre-launch)
__global__ void init_out_kernel(float4* __restrict__ out4,
                                const float* __restrict__ bias,
                                int n4) {
    int i = blockIdx.x * blockDim.x + threadIdx.x;
    if (i < n4) {
        int d = (i & 3) * 4;   // DIM=16 -> 4 float4 per row
        out4[i] = make_float4(bias[d], bias[d + 1], bias[d + 2], bias[d + 3]);
    }
}

// 16 lanes per stream (lane = dim), 16 consecutive tokens per stream.
// Index/rating/seg data loaded as dwordx4, all 16 weight-row gathers issued
// before any use (16 lanes x dword = one coalesced 64B line per row).
// Sorted segment_ids -> register run-length accumulate; ONE atomicAdd per
// lane per segment boundary (16-lane-coalesced 64B atomic).
// Falsified alternatives (keep for the record):
//  - R3/R2: MLP depth 4->16 outstanding: neutral (not latency-starved)
//  - R4: MALL warm of the 64MB table: ~neutral (not miss-latency-bound)
//  - R5: nontemporal loads: +6us (the ~1.46x row reuse needs L2 capture)
//  - R7: float4-per-lane gathers (1KB/instr) + scalar atomics: +10us
//    (WRITE_SIZE 1.8->29MB of atomic RMW traffic; granularity not the wall)
// Surviving model: random-64B distinct-line throughput wall ~1.6-1.8 TB/s.
__global__ __launch_bounds__(256) void features_linear_kernel(
    const int*   __restrict__ ids,
    const float* __restrict__ ratings,
    const int*   __restrict__ segs,
    const float* __restrict__ weight,
    float*       __restrict__ out,
    int total) {
    int tid = blockIdx.x * blockDim.x + threadIdx.x;
    int d = tid & (DIM - 1);
    int stream_id = tid >> 4;
    int t0 = stream_id * K_TOK;
    if (t0 >= total) return;

    float acc = 0.0f;
    int prev = segs[t0];

    if (t0 + K_TOK <= total) {
        const int4*   idv = (const int4*)(ids + t0);
        const float4* rv  = (const float4*)(ratings + t0);
        const int4*   sv  = (const int4*)(segs + t0);

        int4   id0 = idv[0], id1 = idv[1], id2 = idv[2], id3 = idv[3];
        float4 r0  = rv[0],  r1  = rv[1],  r2  = rv[2],  r3  = rv[3];
        int4   s0  = sv[0],  s1  = sv[1],  s2  = sv[2],  s3  = sv[3];

        float w0  = weight[(size_t)id0.x * DIM + d];
        float w1  = weight[(size_t)id0.y * DIM + d];
        float w2  = weight[(size_t)id0.z * DIM + d];
        float w3  = weight[(size_t)id0.w * DIM + d];
        float w4  = weight[(size_t)id1.x * DIM + d];
        float w5  = weight[(size_t)id1.y * DIM + d];
        float w6  = weight[(size_t)id1.z * DIM + d];
        float w7  = weight[(size_t)id1.w * DIM + d];
        float w8  = weight[(size_t)id2.x * DIM + d];
        float w9  = weight[(size_t)id2.y * DIM + d];
        float w10 = weight[(size_t)id2.z * DIM + d];
        float w11 = weight[(size_t)id2.w * DIM + d];
        float w12 = weight[(size_t)id3.x * DIM + d];
        float w13 = weight[(size_t)id3.y * DIM + d];
        float w14 = weight[(size_t)id3.z * DIM + d];
        float w15 = weight[(size_t)id3.w * DIM + d];

        #define STEP(sv_, wv_, rv_)                                        \
            if ((sv_) != prev) {                                           \
                atomicAdd(&out[prev * DIM + d], acc);                      \
                acc = 0.0f; prev = (sv_);                                  \
            }                                                              \
            acc = fmaf((wv_), (rv_), acc);

        STEP(s0.x, w0,  r0.x)  STEP(s0.y, w1,  r0.y)
        STEP(s0.z, w2,  r0.z)  STEP(s0.w, w3,  r0.w)
        STEP(s1.x, w4,  r1.x)  STEP(s1.y, w5,  r1.y)
        STEP(s1.z, w6,  r1.z)  STEP(s1.w, w7,  r1.w)
        STEP(s2.x, w8,  r2.x)  STEP(s2.y, w9,  r2.y)
        STEP(s2.z, w10, r2.z)  STEP(s2.w, w11, r2.w)
        STEP(s3.x, w12, r3.x)  STEP(s3.y, w13, r3.y)
        STEP(s3.z, w14, r3.z)  STEP(s3.w, w15, r3.w)
        #undef STEP
    } else {
        for (int t = t0; t < total; ++t) {
            int seg = segs[t];
            if (seg != prev) {
                atomicAdd(&out[prev * DIM + d], acc);
                acc = 0.0f;
                prev = seg;
            }
            acc = fmaf(weight[(size_t)ids[t] * DIM + d], ratings[t], acc);
        }
    }
    atomicAdd(&out[prev * DIM + d], acc);
}

extern "C" void kernel_launch(void* const* d_in, const int* in_sizes, int n_in,
                              void* d_out, int out_size, void* d_ws, size_t ws_size,
                              hipStream_t stream) {
    const int*   ids     = (const int*)d_in[0];
    const float* ratings = (const float*)d_in[1];
    const int*   segs    = (const int*)d_in[2];
    // d_in[3] = batch_size scalar (unused; batch = out_size / DIM)
    const float* weight  = (const float*)d_in[4];
    const float* bias    = (const float*)d_in[5];
    float* out = (float*)d_out;

    int total = in_sizes[0];

    // 1) initialize output with bias (vectorized)
    {
        int n4 = out_size / 4;
        int threads = 256;
        int blocks = (n4 + threads - 1) / threads;
        init_out_kernel<<<blocks, threads, 0, stream>>>((float4*)out, bias, n4);
    }

    // 2) gather + segmented sum
    {
        int n_streams = (total + K_TOK - 1) / K_TOK;
        long long n_threads = (long long)n_streams * DIM;
        int threads = 256;
        int blocks = (int)((n_threads + threads - 1) / threads);
        features_linear_kernel<<<blocks, threads, 0, stream>>>(
            ids, ratings, segs, weight, out, total);
    }
}